// Round 6
// baseline (4998.757 us; speedup 1.0000x reference)
//
#include <hip/hip_runtime.h>

#define T_LEN 1024
#define HID   128
#define G4    512
#define BCH   4
#define NG    128
#define HB_STR 136   // halves per batch-col row (16B-aligned, 2-way bank alias = free)

typedef _Float16 h2_t   __attribute__((ext_vector_type(2)));
typedef _Float16 f16x8  __attribute__((ext_vector_type(8)));
typedef float    f32x4n __attribute__((ext_vector_type(4)));

__device__ __forceinline__ float fsig(float v) {
  return __builtin_amdgcn_rcpf(1.0f + __expf(-v));
}
__device__ __forceinline__ float ftanh(float v) {
  float a = fabsf(v);
  float e = __expf(-2.0f * a);
  float t = (1.0f - e) * __builtin_amdgcn_rcpf(1.0f + e);
  return copysignf(t, v);
}

#define MFMA16(A, B, C) __builtin_amdgcn_mfma_f32_16x16x32_f16( \
    __builtin_bit_cast(f16x8, (A)), (B), (C), 0, 0, 0)

// ---------------------------------------------------------------------------
// Pack fp32 weights into MFMA A-fragments (fp16), gate-tiled per wave:
// dst[((m*8 + w)*16 + g*4 + kt)*64 + l] = 8 halves of
//   row = g*128 + 16*w + (l&15),  k = 32*kt + (l>>4)*8 .. +8
// m: 0=Whh1, 1=Whh2, 2=Wih2.  Total 24576 uint4 = 384 KB.
// ---------------------------------------------------------------------------
__global__ void __launch_bounds__(256) pack_frag2(
    const float* __restrict__ wa, const float* __restrict__ wb,
    const float* __restrict__ wc, uint4* __restrict__ dst) {
  int idx = blockIdx.x * 256 + threadIdx.x;   // 0..24575
  int l = idx & 63;
  int f = (idx >> 6) & 15;    // g*4 + kt
  int w = (idx >> 10) & 7;
  int m = idx >> 13;
  const float* src = (m == 0) ? wa : (m == 1) ? wb : wc;
  int row = (f >> 2) * HID + 16 * w + (l & 15);
  int k0  = 32 * (f & 3) + (l >> 4) * 8;
  const float* s = src + (size_t)row * HID + k0;
  unsigned int r[4];
#pragma unroll
  for (int q = 0; q < 4; ++q) {
    h2_t h;
    h.x = (_Float16)s[2 * q];
    h.y = (_Float16)s[2 * q + 1];
    r[q] = __builtin_bit_cast(unsigned int, h);
  }
  dst[idx] = make_uint4(r[0], r[1], r[2], r[3]);
}

// ---------------------------------------------------------------------------
// 2-barrier MFMA kernel. 128 WGs x 512 thr, 4 batches/WG. Wave w owns units
// [16w,16w+16) for ALL four gates of all three matrices (A-frags register/
// AGPR-resident). Lane l: batch col = l&15 (0..3 valid), units u0..u0+3 with
// u0 = 16w + (l>>4)*4. Gates activate fully in-register; c1/c2 in registers.
// h1/h2 in LDS fp16 [col][unit] (HB_STR pad); hB1 double-buffered.
// ---------------------------------------------------------------------------
__global__ void __launch_bounds__(512, 2) lstm_mfma2(
    const float* __restrict__ xin, const float* __restrict__ Wih1,
    const float* __restrict__ bih1, const float* __restrict__ bhh1,
    const uint4* __restrict__ wfrag,
    const float* __restrict__ bih2, const float* __restrict__ bhh2,
    const float* __restrict__ Wout, const float* __restrict__ bout,
    float* __restrict__ outp)
{
  __shared__ _Float16 hB1[2][16 * HB_STR];
  __shared__ _Float16 hB2[16 * HB_STR];
  __shared__ float    prt[8][16];
  __shared__ float    xb[2][4];

  const int tid = threadIdx.x;
  const int l   = tid & 63;
  const int w   = tid >> 6;
  const int b0  = blockIdx.x * BCH;
  const int col = l & 15;
  const int qu  = l >> 4;
  const int u0  = 16 * w + qu * 4;

  // ---- one-time: A-fragments into registers/AGPRs ----
  f32x4n A1[16], A2[16], AI[16];
#pragma unroll
  for (int f = 0; f < 16; ++f) {
    A1[f] = __builtin_bit_cast(f32x4n, wfrag[((0 * 8 + w) * 16 + f) * 64 + l]);
    A2[f] = __builtin_bit_cast(f32x4n, wfrag[((1 * 8 + w) * 16 + f) * 64 + l]);
    AI[f] = __builtin_bit_cast(f32x4n, wfrag[((2 * 8 + w) * 16 + f) * 64 + l]);
  }
#pragma unroll
  for (int f = 0; f < 16; ++f)
    asm volatile("" : "+v"(A1[f]), "+v"(A2[f]), "+v"(AI[f]));

  // ---- per-lane constants (unit-indexed, 4 rows per gate) ----
  float b1i[4], b1f[4], b1g[4], b1o[4];
  float w1i[4], w1f[4], w1g[4], w1o[4];
  float b2i[4], b2f[4], b2g[4], b2o[4];
  float woc[4];
#pragma unroll
  for (int r = 0; r < 4; ++r) {
    int u = u0 + r;
    b1i[r] = bih1[u]           + bhh1[u];
    b1f[r] = bih1[HID + u]     + bhh1[HID + u];
    b1g[r] = bih1[2 * HID + u] + bhh1[2 * HID + u];
    b1o[r] = bih1[3 * HID + u] + bhh1[3 * HID + u];
    w1i[r] = Wih1[u];
    w1f[r] = Wih1[HID + u];
    w1g[r] = Wih1[2 * HID + u];
    w1o[r] = Wih1[3 * HID + u];
    b2i[r] = bih2[u]           + bhh2[u];
    b2f[r] = bih2[HID + u]     + bhh2[HID + u];
    b2g[r] = bih2[2 * HID + u] + bhh2[2 * HID + u];
    b2o[r] = bih2[3 * HID + u] + bhh2[3 * HID + u];
    woc[r] = Wout[u];
  }
  const float bo = bout[0];
  float c1r[4] = {0.f, 0.f, 0.f, 0.f};
  float c2r[4] = {0.f, 0.f, 0.f, 0.f};

  // ---- zero LDS ----
  {
    unsigned int* z1 = (unsigned int*)&hB1[0][0];
    for (int i = tid; i < 2 * 16 * HB_STR / 2; i += 512) z1[i] = 0u;
    unsigned int* z2 = (unsigned int*)&hB2[0];
    for (int i = tid; i < 16 * HB_STR / 2; i += 512) z2[i] = 0u;
    if (tid < BCH) xb[0][tid] = xin[(size_t)(b0 + tid) * T_LEN];
  }
  __syncthreads();

  const int boff = col * HB_STR + qu * 8;   // B-fragment base (halves)

  for (int t = 0; t < T_LEN; ++t) {
    const int p = t & 1;
    const int pn = p ^ 1;

    float xpref = 0.f;
    if (((tid & ~3) == 128) && (t + 1) < T_LEN)
      xpref = xin[(size_t)(b0 + (tid & 3)) * T_LEN + t + 1];

    // ================= P1: gates1 + Whh2*h2 partial =================
    f16x8 B1a = *reinterpret_cast<const f16x8*>(&hB1[p][boff +  0]);
    f16x8 B1b = *reinterpret_cast<const f16x8*>(&hB1[p][boff + 32]);
    f16x8 B1c = *reinterpret_cast<const f16x8*>(&hB1[p][boff + 64]);
    f16x8 B1d = *reinterpret_cast<const f16x8*>(&hB1[p][boff + 96]);
    f16x8 B2a = *reinterpret_cast<const f16x8*>(&hB2[boff +  0]);
    f16x8 B2b = *reinterpret_cast<const f16x8*>(&hB2[boff + 32]);
    f16x8 B2c = *reinterpret_cast<const f16x8*>(&hB2[boff + 64]);
    f16x8 B2d = *reinterpret_cast<const f16x8*>(&hB2[boff + 96]);

    f32x4n C1i = {0,0,0,0}, C1f = {0,0,0,0}, C1g = {0,0,0,0}, C1o = {0,0,0,0};
    f32x4n C2i = {0,0,0,0}, C2f = {0,0,0,0}, C2g = {0,0,0,0}, C2o = {0,0,0,0};

    C1i = MFMA16(A1[ 0], B1a, C1i); C1i = MFMA16(A1[ 1], B1b, C1i);
    C1i = MFMA16(A1[ 2], B1c, C1i); C1i = MFMA16(A1[ 3], B1d, C1i);
    C1f = MFMA16(A1[ 4], B1a, C1f); C1f = MFMA16(A1[ 5], B1b, C1f);
    C1f = MFMA16(A1[ 6], B1c, C1f); C1f = MFMA16(A1[ 7], B1d, C1f);
    C1g = MFMA16(A1[ 8], B1a, C1g); C1g = MFMA16(A1[ 9], B1b, C1g);
    C1g = MFMA16(A1[10], B1c, C1g); C1g = MFMA16(A1[11], B1d, C1g);
    C1o = MFMA16(A1[12], B1a, C1o); C1o = MFMA16(A1[13], B1b, C1o);
    C1o = MFMA16(A1[14], B1c, C1o); C1o = MFMA16(A1[15], B1d, C1o);

    C2i = MFMA16(A2[ 0], B2a, C2i); C2i = MFMA16(A2[ 1], B2b, C2i);
    C2i = MFMA16(A2[ 2], B2c, C2i); C2i = MFMA16(A2[ 3], B2d, C2i);
    C2f = MFMA16(A2[ 4], B2a, C2f); C2f = MFMA16(A2[ 5], B2b, C2f);
    C2f = MFMA16(A2[ 6], B2c, C2f); C2f = MFMA16(A2[ 7], B2d, C2f);
    C2g = MFMA16(A2[ 8], B2a, C2g); C2g = MFMA16(A2[ 9], B2b, C2g);
    C2g = MFMA16(A2[10], B2c, C2g); C2g = MFMA16(A2[11], B2d, C2g);
    C2o = MFMA16(A2[12], B2a, C2o); C2o = MFMA16(A2[13], B2b, C2o);
    C2o = MFMA16(A2[14], B2c, C2o); C2o = MFMA16(A2[15], B2d, C2o);

    // ---- act1 + c1 + h1 (in-register) ----
    {
      float xcol = xb[p][col & 3];
      float h1v[4];
#pragma unroll
      for (int r = 0; r < 4; ++r) {
        float vi = C1i[r] + fmaf(w1i[r], xcol, b1i[r]);
        float vf = C1f[r] + fmaf(w1f[r], xcol, b1f[r]);
        float vg = C1g[r] + fmaf(w1g[r], xcol, b1g[r]);
        float vo = C1o[r] + fmaf(w1o[r], xcol, b1o[r]);
        float si = fsig(vi), sf = fsig(vf), tg = ftanh(vg), so = fsig(vo);
        c1r[r] = fmaf(sf, c1r[r], si * tg);
        h1v[r] = so * ftanh(c1r[r]);
      }
      h2_t plo, phi;
      plo.x = (_Float16)h1v[0]; plo.y = (_Float16)h1v[1];
      phi.x = (_Float16)h1v[2]; phi.y = (_Float16)h1v[3];
      uint2 pk;
      pk.x = __builtin_bit_cast(unsigned int, plo);
      pk.y = __builtin_bit_cast(unsigned int, phi);
      *reinterpret_cast<uint2*>(&hB1[pn][col * HB_STR + u0]) = pk;
    }
    if (((tid & ~3) == 128) && (t + 1) < T_LEN)
      xb[pn][tid & 3] = xpref;
    __syncthreads();   // ---- barrier 1 ----

    // ================= P2: gates2 += Wih2 * h1(t) =================
    f16x8 N1a = *reinterpret_cast<const f16x8*>(&hB1[pn][boff +  0]);
    f16x8 N1b = *reinterpret_cast<const f16x8*>(&hB1[pn][boff + 32]);
    f16x8 N1c = *reinterpret_cast<const f16x8*>(&hB1[pn][boff + 64]);
    f16x8 N1d = *reinterpret_cast<const f16x8*>(&hB1[pn][boff + 96]);

    C2i = MFMA16(AI[ 0], N1a, C2i); C2i = MFMA16(AI[ 1], N1b, C2i);
    C2i = MFMA16(AI[ 2], N1c, C2i); C2i = MFMA16(AI[ 3], N1d, C2i);
    C2f = MFMA16(AI[ 4], N1a, C2f); C2f = MFMA16(AI[ 5], N1b, C2f);
    C2f = MFMA16(AI[ 6], N1c, C2f); C2f = MFMA16(AI[ 7], N1d, C2f);
    C2g = MFMA16(AI[ 8], N1a, C2g); C2g = MFMA16(AI[ 9], N1b, C2g);
    C2g = MFMA16(AI[10], N1c, C2g); C2g = MFMA16(AI[11], N1d, C2g);
    C2o = MFMA16(AI[12], N1a, C2o); C2o = MFMA16(AI[13], N1b, C2o);
    C2o = MFMA16(AI[14], N1c, C2o); C2o = MFMA16(AI[15], N1d, C2o);

    // ---- act2 + c2 + h2 + out partial (in-register) ----
    {
      float po = 0.f;
      float h2v[4];
#pragma unroll
      for (int r = 0; r < 4; ++r) {
        float vi = C2i[r] + b2i[r];
        float vf = C2f[r] + b2f[r];
        float vg = C2g[r] + b2g[r];
        float vo = C2o[r] + b2o[r];
        float si = fsig(vi), sf = fsig(vf), tg = ftanh(vg), so = fsig(vo);
        c2r[r] = fmaf(sf, c2r[r], si * tg);
        h2v[r] = so * ftanh(c2r[r]);
        po = fmaf(woc[r], h2v[r], po);
      }
      h2_t plo, phi;
      plo.x = (_Float16)h2v[0]; plo.y = (_Float16)h2v[1];
      phi.x = (_Float16)h2v[2]; phi.y = (_Float16)h2v[3];
      uint2 pk;
      pk.x = __builtin_bit_cast(unsigned int, plo);
      pk.y = __builtin_bit_cast(unsigned int, phi);
      *reinterpret_cast<uint2*>(&hB2[col * HB_STR + u0]) = pk;
      po += __shfl_xor(po, 16, 64);
      po += __shfl_xor(po, 32, 64);
      if (l < 16) prt[w][l] = po;
    }
    __syncthreads();   // ---- barrier 2 ----

    if (tid < 16) {
      float s = prt[0][tid] + prt[1][tid] + prt[2][tid] + prt[3][tid]
              + prt[4][tid] + prt[5][tid] + prt[6][tid] + prt[7][tid];
      if (tid < BCH)
        outp[(size_t)(b0 + tid) * T_LEN + t] = s + bo;
    }
  }
}

// ---------------------------------------------------------------------------
// Fallback (round-1, known-correct fp32 path)
// ---------------------------------------------------------------------------
__global__ void __launch_bounds__(512) transpose_w(
    const float* __restrict__ w1, const float* __restrict__ w2,
    const float* __restrict__ w3, float* __restrict__ o) {
  int m = blockIdx.y;
  const float* src = (m == 0) ? w1 : (m == 1) ? w2 : w3;
  float* dst = o + (size_t)m * G4 * HID;
  int idx = blockIdx.x * 512 + threadIdx.x;
  int j = idx >> 7;
  int k = idx & (HID - 1);
  dst[k * G4 + j] = src[idx];
}

__device__ __forceinline__ float gact(float v, int gt) {
  return (gt == 2) ? ftanh(v) : fsig(v);
}

__device__ __forceinline__ void store_out4(const float4* h2buf, float wo0, float wo1,
                                           float bo, int tid, int b0,
                                           float* __restrict__ outp, int t) {
  float4 ha = h2buf[tid];
  float4 hb = h2buf[tid + 64];
  float p0 = wo0 * ha.x + wo1 * hb.x;
  float p1 = wo0 * ha.y + wo1 * hb.y;
  float p2 = wo0 * ha.z + wo1 * hb.z;
  float p3 = wo0 * ha.w + wo1 * hb.w;
#pragma unroll
  for (int off = 1; off < 64; off <<= 1) {
    p0 += __shfl_xor(p0, off, 64);
    p1 += __shfl_xor(p1, off, 64);
    p2 += __shfl_xor(p2, off, 64);
    p3 += __shfl_xor(p3, off, 64);
  }
  if (tid < BCH) {
    float v = (tid == 0) ? p0 : (tid == 1) ? p1 : (tid == 2) ? p2 : p3;
    outp[(size_t)(b0 + tid) * T_LEN + t] = v + bo;
  }
}

__global__ void __launch_bounds__(512) lstm_fused(
    const float* __restrict__ xin, const float* __restrict__ Wih1,
    const float* __restrict__ bih1, const float* __restrict__ bhh1,
    const float* __restrict__ Whh1, const float* __restrict__ Wih2,
    const float* __restrict__ Whh2, int sk, int sj,
    const float* __restrict__ bih2, const float* __restrict__ bhh2,
    const float* __restrict__ Wout, const float* __restrict__ bout,
    float* __restrict__ outp) {
  __shared__ float4 h1buf[HID];
  __shared__ float4 h2buf[HID];
  __shared__ float4 g1[G4];
  __shared__ float4 g2[G4];
  __shared__ float xb[2][BCH];

  const int tid = threadIdx.x;
  const int b0 = blockIdx.x * BCH;
  const int gt = tid >> 7;

  float bias1 = bih1[tid] + bhh1[tid];
  float bias2 = bih2[tid] + bhh2[tid];
  float wi1 = Wih1[tid];
  float c1_0 = 0.f, c1_1 = 0.f, c1_2 = 0.f, c1_3 = 0.f;
  float c2_0 = 0.f, c2_1 = 0.f, c2_2 = 0.f, c2_3 = 0.f;
  float wo0 = 0.f, wo1 = 0.f, bo = 0.f;
  if (tid < 64) { wo0 = Wout[tid]; wo1 = Wout[tid + 64]; bo = bout[0]; }
  if (tid < HID) {
    h1buf[tid] = make_float4(0.f, 0.f, 0.f, 0.f);
    h2buf[tid] = make_float4(0.f, 0.f, 0.f, 0.f);
  }
  if (tid < BCH) xb[0][tid] = xin[(b0 + tid) * T_LEN];
  __syncthreads();

  const float* wp1  = Whh1 + tid * sj;
  const float* wp2  = Whh2 + tid * sj;
  const float* wpi2 = Wih2 + tid * sj;

  for (int t = 0; t < T_LEN; ++t) {
    float xpref = 0.f;
    if ((tid & ~3) == 128 && (t + 1) < T_LEN)
      xpref = xin[(b0 + (tid & 3)) * T_LEN + t + 1];

    if (tid < 64 && t > 0) store_out4(h2buf, wo0, wo1, bo, tid, b0, outp, t - 1);

    float xv0 = xb[t & 1][0], xv1 = xb[t & 1][1];
    float xv2 = xb[t & 1][2], xv3 = xb[t & 1][3];
    float a10 = fmaf(wi1, xv0, bias1);
    float a11 = fmaf(wi1, xv1, bias1);
    float a12 = fmaf(wi1, xv2, bias1);
    float a13 = fmaf(wi1, xv3, bias1);
    float a20 = bias2, a21 = bias2, a22 = bias2, a23 = bias2;
#pragma unroll 8
    for (int k = 0; k < HID; ++k) {
      float w1 = wp1[k * sk];
      float w2 = wp2[k * sk];
      float4 hv1 = h1buf[k];
      float4 hv2 = h2buf[k];
      a10 = fmaf(w1, hv1.x, a10);
      a11 = fmaf(w1, hv1.y, a11);
      a12 = fmaf(w1, hv1.z, a12);
      a13 = fmaf(w1, hv1.w, a13);
      a20 = fmaf(w2, hv2.x, a20);
      a21 = fmaf(w2, hv2.y, a21);
      a22 = fmaf(w2, hv2.z, a22);
      a23 = fmaf(w2, hv2.w, a23);
    }
    float4 A1v;
    A1v.x = gact(a10, gt); A1v.y = gact(a11, gt);
    A1v.z = gact(a12, gt); A1v.w = gact(a13, gt);
    g1[tid] = A1v;
    __syncthreads();

    if (tid < HID) {
      float4 iv = g1[tid], fv = g1[tid + HID];
      float4 gv = g1[tid + 2 * HID], ov = g1[tid + 3 * HID];
      c1_0 = fmaf(fv.x, c1_0, iv.x * gv.x);
      c1_1 = fmaf(fv.y, c1_1, iv.y * gv.y);
      c1_2 = fmaf(fv.z, c1_2, iv.z * gv.z);
      c1_3 = fmaf(fv.w, c1_3, iv.w * gv.w);
      float4 h;
      h.x = ov.x * ftanh(c1_0);
      h.y = ov.y * ftanh(c1_1);
      h.z = ov.z * ftanh(c1_2);
      h.w = ov.w * ftanh(c1_3);
      h1buf[tid] = h;
    }
    __syncthreads();

#pragma unroll 8
    for (int k = 0; k < HID; ++k) {
      float wv = wpi2[k * sk];
      float4 hv = h1buf[k];
      a20 = fmaf(wv, hv.x, a20);
      a21 = fmaf(wv, hv.y, a21);
      a22 = fmaf(wv, hv.z, a22);
      a23 = fmaf(wv, hv.w, a23);
    }
    float4 A2v;
    A2v.x = gact(a20, gt); A2v.y = gact(a21, gt);
    A2v.z = gact(a22, gt); A2v.w = gact(a23, gt);
    g2[tid] = A2v;
    __syncthreads();

    if (tid < HID) {
      float4 iv = g2[tid], fv = g2[tid + HID];
      float4 gv = g2[tid + 2 * HID], ov = g2[tid + 3 * HID];
      c2_0 = fmaf(fv.x, c2_0, iv.x * gv.x);
      c2_1 = fmaf(fv.y, c2_1, iv.y * gv.y);
      c2_2 = fmaf(fv.z, c2_2, iv.z * gv.z);
      c2_3 = fmaf(fv.w, c2_3, iv.w * gv.w);
      float4 h;
      h.x = ov.x * ftanh(c2_0);
      h.y = ov.y * ftanh(c2_1);
      h.z = ov.z * ftanh(c2_2);
      h.w = ov.w * ftanh(c2_3);
      h2buf[tid] = h;
    } else if ((tid & ~3) == 128 && (t + 1) < T_LEN) {
      xb[(t + 1) & 1][tid & 3] = xpref;
    }
    __syncthreads();
  }
  if (tid < 64) store_out4(h2buf, wo0, wo1, bo, tid, b0, outp, T_LEN - 1);
}

extern "C" void kernel_launch(void* const* d_in, const int* in_sizes, int n_in,
                              void* d_out, int out_size, void* d_ws, size_t ws_size,
                              hipStream_t stream) {
  const float* xin  = (const float*)d_in[0];
  const float* Wih1 = (const float*)d_in[1];
  const float* Whh1 = (const float*)d_in[2];
  const float* bih1 = (const float*)d_in[3];
  const float* bhh1 = (const float*)d_in[4];
  const float* Wih2 = (const float*)d_in[5];
  const float* Whh2 = (const float*)d_in[6];
  const float* bih2 = (const float*)d_in[7];
  const float* bhh2 = (const float*)d_in[8];
  const float* Wout = (const float*)d_in[9];
  const float* bout = (const float*)d_in[10];
  float* outp = (float*)d_out;

  const size_t needFr = (size_t)3 * 8 * 16 * 64 * sizeof(uint4);  // 384 KB
  if (ws_size >= needFr) {
    uint4* wfrag = (uint4*)d_ws;
    pack_frag2<<<96, 256, 0, stream>>>(Whh1, Whh2, Wih2, wfrag);
    lstm_mfma2<<<NG, 512, 0, stream>>>(
        xin, Wih1, bih1, bhh1, wfrag, bih2, bhh2, Wout, bout, outp);
    return;
  }

  // fallback: round-1 fp32 kernel
  size_t need = (size_t)3 * G4 * HID * sizeof(float);
  if (ws_size >= need) {
    float* wt = (float*)d_ws;
    transpose_w<<<dim3(128, 3), 512, 0, stream>>>(Whh1, Wih2, Whh2, wt);
    lstm_fused<<<NG, 512, 0, stream>>>(
        xin, Wih1, bih1, bhh1,
        wt, wt + (size_t)G4 * HID, wt + (size_t)2 * G4 * HID, G4, 1,
        bih2, bhh2, Wout, bout, outp);
  } else {
    lstm_fused<<<NG, 512, 0, stream>>>(
        xin, Wih1, bih1, bhh1,
        Whh1, Wih2, Whh2, 1, HID,
        bih2, bhh2, Wout, bout, outp);
  }
}

// Round 7
// 3083.310 us; speedup vs baseline: 1.6212x; 1.6212x over previous
//
#include <hip/hip_runtime.h>

#define T_LEN 1024
#define HID   128
#define G4    512
#define BCH   4
#define NG    128
#define HB_STR 136   // halves per batch-col row: 272 B = 16*17 -> conflict-free b128 frag reads

typedef _Float16 h2_t   __attribute__((ext_vector_type(2)));
typedef _Float16 f16x8  __attribute__((ext_vector_type(8)));
typedef float    f32x4n __attribute__((ext_vector_type(4)));

__device__ __forceinline__ float fsig(float v) {
  return __builtin_amdgcn_rcpf(1.0f + __expf(-v));
}
__device__ __forceinline__ float ftanh(float v) {
  float a = fabsf(v);
  float e = __expf(-2.0f * a);
  float t = (1.0f - e) * __builtin_amdgcn_rcpf(1.0f + e);
  return copysignf(t, v);
}

#define MFMA16(A, B, C) __builtin_amdgcn_mfma_f32_16x16x32_f16( \
    __builtin_bit_cast(f16x8, (A)), (B), (C), 0, 0, 0)

// ---------------------------------------------------------------------------
// Pack fp32 weights into MFMA A-fragments (fp16), gate-tiled per wave
// (identical to R5/R6 — validated): dst[((m*8+w)*16 + g*4+kt)*64 + l] =
// 8 halves of row = g*128 + 16w + (l&15), k = 32*kt + (l>>4)*8.
// m: 0=Whh1, 1=Whh2, 2=Wih2.
// ---------------------------------------------------------------------------
__global__ void __launch_bounds__(256) pack_frag2(
    const float* __restrict__ wa, const float* __restrict__ wb,
    const float* __restrict__ wc, uint4* __restrict__ dst) {
  int idx = blockIdx.x * 256 + threadIdx.x;   // 0..24575
  int l = idx & 63;
  int f = (idx >> 6) & 15;
  int w = (idx >> 10) & 7;
  int m = idx >> 13;
  const float* src = (m == 0) ? wa : (m == 1) ? wb : wc;
  int row = (f >> 2) * HID + 16 * w + (l & 15);
  int k0  = 32 * (f & 3) + (l >> 4) * 8;
  const float* s = src + (size_t)row * HID + k0;
  unsigned int r[4];
#pragma unroll
  for (int q = 0; q < 4; ++q) {
    h2_t h;
    h.x = (_Float16)s[2 * q];
    h.y = (_Float16)s[2 * q + 1];
    r[q] = __builtin_bit_cast(unsigned int, h);
  }
  dst[idx] = make_uint4(r[0], r[1], r[2], r[3]);
}

// ---------------------------------------------------------------------------
// Layer-pipelined MFMA kernel, 3 barriers/step.
// Iteration i: layer-2 of step t=i  +  layer-1 of step t+1.
//   A : C2 += Wih2*h1(t)  and  C1 = Whh1*h1(t)   (one h1 B-frag read, 32 MFMA)
//       scatter C2 (complete: carry held Whh2*h2(t-1))
//   B : state-2 (all 512 thr, thread=(u,b)): gather g2, act, c2,h2; out-reduce;
//       scatter C1; commit x(t+1)
//   CD: store out(t); C2 = Whh2*h2(t) (carry);  state-1: gather g1 (+x term),
//       act, c1, h1(t+1)   -- MFMA overlaps the act VALU/trans work
// ---------------------------------------------------------------------------
__global__ void __launch_bounds__(512, 2) lstm_pipe(
    const float* __restrict__ xin, const float* __restrict__ Wih1,
    const float* __restrict__ bih1, const float* __restrict__ bhh1,
    const uint4* __restrict__ wfrag,
    const float* __restrict__ bih2, const float* __restrict__ bhh2,
    const float* __restrict__ Wout, const float* __restrict__ bout,
    float* __restrict__ outp)
{
  __shared__ _Float16 hB1[16 * HB_STR];   // [col 0..15][unit 0..127] fp16
  __shared__ _Float16 hB2[16 * HB_STR];
  __shared__ float    g1b[G4 * 4];        // raw gates, [row][batch]
  __shared__ float    g2b[G4 * 4];
  __shared__ float    prt[8][4];
  __shared__ float    xb[4];

  const int tid = threadIdx.x;
  const int l   = tid & 63;
  const int w   = tid >> 6;
  const int col = l & 15;
  const int qu  = l >> 4;
  const int b0  = blockIdx.x * BCH;
  const int u   = tid >> 2;       // state role: unit 0..127
  const int b   = tid & 3;        // state role: batch 0..3

  // ---- A-fragments into registers/AGPRs (one-time) ----
  f32x4n A1[16], A2[16], AI[16];
#pragma unroll
  for (int f = 0; f < 16; ++f) {
    A1[f] = __builtin_bit_cast(f32x4n, wfrag[((0 * 8 + w) * 16 + f) * 64 + l]);
    A2[f] = __builtin_bit_cast(f32x4n, wfrag[((1 * 8 + w) * 16 + f) * 64 + l]);
    AI[f] = __builtin_bit_cast(f32x4n, wfrag[((2 * 8 + w) * 16 + f) * 64 + l]);
  }
#pragma unroll
  for (int f = 0; f < 16; ++f)
    asm volatile("" : "+v"(A1[f]), "+v"(A2[f]), "+v"(AI[f]));

  // ---- state-role constants ----
  float b1c[4], w1c[4], b2c[4];
#pragma unroll
  for (int g = 0; g < 4; ++g) {
    b1c[g] = bih1[g * HID + u] + bhh1[g * HID + u];
    w1c[g] = Wih1[g * HID + u];
    b2c[g] = bih2[g * HID + u] + bhh2[g * HID + u];
  }
  const float wou = Wout[u];
  const float bo  = bout[0];
  float c1 = 0.f, c2 = 0.f;

  // ---- zero h buffers (cols 4..15 stay zero forever) ----
  {
    unsigned int* z1 = (unsigned int*)hB1;
    unsigned int* z2 = (unsigned int*)hB2;
    for (int i = tid; i < 16 * HB_STR / 2; i += 512) { z1[i] = 0u; z2[i] = 0u; }
    if (tid < 4) xb[tid] = xin[(size_t)(b0 + tid) * T_LEN];
  }
  __syncthreads();

  // ---- prologue: h1(0) = layer1(x(0), h1=0, c1=0) ----
  {
    float xv = xb[b];
    float vi = fmaf(w1c[0], xv, b1c[0]);
    float vf = fmaf(w1c[1], xv, b1c[1]);
    float vg = fmaf(w1c[2], xv, b1c[2]);
    float vo = fmaf(w1c[3], xv, b1c[3]);
    (void)vf;
    float si = fsig(vi), tg = ftanh(vg), so = fsig(vo);
    c1 = si * tg;                     // f*0 + i*g
    float h1v = so * ftanh(c1);
    hB1[b * HB_STR + u] = (_Float16)h1v;
  }
  __syncthreads();

  const int boff  = col * HB_STR + qu * 8;
  const int urow0 = 16 * w + qu * 4;

  f32x4n C2i = {0,0,0,0}, C2f = {0,0,0,0}, C2g = {0,0,0,0}, C2o = {0,0,0,0};

  for (int t = 0; t < T_LEN; ++t) {
    // ================= A: MFMA burst on h1(t) =================
    float xl = 0.f;
    if (tid < 4 && (t + 1) < T_LEN)
      xl = xin[(size_t)(b0 + tid) * T_LEN + (t + 1)];

    f16x8 Bh0 = *reinterpret_cast<const f16x8*>(&hB1[boff +  0]);
    f16x8 Bh1 = *reinterpret_cast<const f16x8*>(&hB1[boff + 32]);
    f16x8 Bh2 = *reinterpret_cast<const f16x8*>(&hB1[boff + 64]);
    f16x8 Bh3 = *reinterpret_cast<const f16x8*>(&hB1[boff + 96]);

    f32x4n C1i = {0,0,0,0}, C1f = {0,0,0,0}, C1g = {0,0,0,0}, C1o = {0,0,0,0};

    C1i = MFMA16(A1[ 0], Bh0, C1i); C1i = MFMA16(A1[ 1], Bh1, C1i);
    C1i = MFMA16(A1[ 2], Bh2, C1i); C1i = MFMA16(A1[ 3], Bh3, C1i);
    C1f = MFMA16(A1[ 4], Bh0, C1f); C1f = MFMA16(A1[ 5], Bh1, C1f);
    C1f = MFMA16(A1[ 6], Bh2, C1f); C1f = MFMA16(A1[ 7], Bh3, C1f);
    C1g = MFMA16(A1[ 8], Bh0, C1g); C1g = MFMA16(A1[ 9], Bh1, C1g);
    C1g = MFMA16(A1[10], Bh2, C1g); C1g = MFMA16(A1[11], Bh3, C1g);
    C1o = MFMA16(A1[12], Bh0, C1o); C1o = MFMA16(A1[13], Bh1, C1o);
    C1o = MFMA16(A1[14], Bh2, C1o); C1o = MFMA16(A1[15], Bh3, C1o);

    C2i = MFMA16(AI[ 0], Bh0, C2i); C2i = MFMA16(AI[ 1], Bh1, C2i);
    C2i = MFMA16(AI[ 2], Bh2, C2i); C2i = MFMA16(AI[ 3], Bh3, C2i);
    C2f = MFMA16(AI[ 4], Bh0, C2f); C2f = MFMA16(AI[ 5], Bh1, C2f);
    C2f = MFMA16(AI[ 6], Bh2, C2f); C2f = MFMA16(AI[ 7], Bh3, C2f);
    C2g = MFMA16(AI[ 8], Bh0, C2g); C2g = MFMA16(AI[ 9], Bh1, C2g);
    C2g = MFMA16(AI[10], Bh2, C2g); C2g = MFMA16(AI[11], Bh3, C2g);
    C2o = MFMA16(AI[12], Bh0, C2o); C2o = MFMA16(AI[13], Bh1, C2o);
    C2o = MFMA16(AI[14], Bh2, C2o); C2o = MFMA16(AI[15], Bh3, C2o);

    if (col < 4) {
#pragma unroll
      for (int r = 0; r < 4; ++r) {
        g2b[((0 * HID + urow0 + r) << 2) + col] = C2i[r];
        g2b[((1 * HID + urow0 + r) << 2) + col] = C2f[r];
        g2b[((2 * HID + urow0 + r) << 2) + col] = C2g[r];
        g2b[((3 * HID + urow0 + r) << 2) + col] = C2o[r];
      }
    }
    __syncthreads();   // ---- barrier 1 ----

    // ================= B: state-2 (+ scatter C1, commit x) =================
    {
      float v0 = g2b[((0 * HID + u) << 2) + b] + b2c[0];
      float v1 = g2b[((1 * HID + u) << 2) + b] + b2c[1];
      float v2 = g2b[((2 * HID + u) << 2) + b] + b2c[2];
      float v3 = g2b[((3 * HID + u) << 2) + b] + b2c[3];
      float si = fsig(v0), sf = fsig(v1), tg = ftanh(v2), so = fsig(v3);
      c2 = fmaf(sf, c2, si * tg);
      float h2v = so * ftanh(c2);
      hB2[b * HB_STR + u] = (_Float16)h2v;
      float po = wou * h2v;
      po += __shfl_xor(po, 4, 64);
      po += __shfl_xor(po, 8, 64);
      po += __shfl_xor(po, 16, 64);
      po += __shfl_xor(po, 32, 64);
      if (l < 4) prt[w][l] = po;
    }
    if (col < 4) {
#pragma unroll
      for (int r = 0; r < 4; ++r) {
        g1b[((0 * HID + urow0 + r) << 2) + col] = C1i[r];
        g1b[((1 * HID + urow0 + r) << 2) + col] = C1f[r];
        g1b[((2 * HID + urow0 + r) << 2) + col] = C1g[r];
        g1b[((3 * HID + urow0 + r) << 2) + col] = C1o[r];
      }
    }
    if (tid < 4) xb[tid] = xl;
    __syncthreads();   // ---- barrier 2 ----

    // ================= CD: out + carry-MFMA + state-1 =================
    if (tid < 4) {
      float s = prt[0][tid] + prt[1][tid] + prt[2][tid] + prt[3][tid]
              + prt[4][tid] + prt[5][tid] + prt[6][tid] + prt[7][tid];
      outp[(size_t)(b0 + tid) * T_LEN + t] = s + bo;
    }

    f16x8 Dh0 = *reinterpret_cast<const f16x8*>(&hB2[boff +  0]);
    f16x8 Dh1 = *reinterpret_cast<const f16x8*>(&hB2[boff + 32]);
    f16x8 Dh2 = *reinterpret_cast<const f16x8*>(&hB2[boff + 64]);
    f16x8 Dh3 = *reinterpret_cast<const f16x8*>(&hB2[boff + 96]);

    C2i = (f32x4n){0,0,0,0};
    C2f = (f32x4n){0,0,0,0};
    C2g = (f32x4n){0,0,0,0};
    C2o = (f32x4n){0,0,0,0};
    C2i = MFMA16(A2[ 0], Dh0, C2i); C2i = MFMA16(A2[ 1], Dh1, C2i);
    C2i = MFMA16(A2[ 2], Dh2, C2i); C2i = MFMA16(A2[ 3], Dh3, C2i);
    C2f = MFMA16(A2[ 4], Dh0, C2f); C2f = MFMA16(A2[ 5], Dh1, C2f);
    C2f = MFMA16(A2[ 6], Dh2, C2f); C2f = MFMA16(A2[ 7], Dh3, C2f);
    C2g = MFMA16(A2[ 8], Dh0, C2g); C2g = MFMA16(A2[ 9], Dh1, C2g);
    C2g = MFMA16(A2[10], Dh2, C2g); C2g = MFMA16(A2[11], Dh3, C2g);
    C2o = MFMA16(A2[12], Dh0, C2o); C2o = MFMA16(A2[13], Dh1, C2o);
    C2o = MFMA16(A2[14], Dh2, C2o); C2o = MFMA16(A2[15], Dh3, C2o);

    {
      float xv = xb[b];
      float v0 = g1b[((0 * HID + u) << 2) + b] + fmaf(w1c[0], xv, b1c[0]);
      float v1 = g1b[((1 * HID + u) << 2) + b] + fmaf(w1c[1], xv, b1c[1]);
      float v2 = g1b[((2 * HID + u) << 2) + b] + fmaf(w1c[2], xv, b1c[2]);
      float v3 = g1b[((3 * HID + u) << 2) + b] + fmaf(w1c[3], xv, b1c[3]);
      float si = fsig(v0), sf = fsig(v1), tg = ftanh(v2), so = fsig(v3);
      c1 = fmaf(sf, c1, si * tg);
      float h1v = so * ftanh(c1);
      hB1[b * HB_STR + u] = (_Float16)h1v;
    }
    __syncthreads();   // ---- barrier 3 ----
  }
}

// ---------------------------------------------------------------------------
// Fallback (round-1, known-correct fp32 path)
// ---------------------------------------------------------------------------
__global__ void __launch_bounds__(512) transpose_w(
    const float* __restrict__ w1, const float* __restrict__ w2,
    const float* __restrict__ w3, float* __restrict__ o) {
  int m = blockIdx.y;
  const float* src = (m == 0) ? w1 : (m == 1) ? w2 : w3;
  float* dst = o + (size_t)m * G4 * HID;
  int idx = blockIdx.x * 512 + threadIdx.x;
  int j = idx >> 7;
  int k = idx & (HID - 1);
  dst[k * G4 + j] = src[idx];
}

__device__ __forceinline__ float gact(float v, int gt) {
  return (gt == 2) ? ftanh(v) : fsig(v);
}

__device__ __forceinline__ void store_out4(const float4* h2buf, float wo0, float wo1,
                                           float bo, int tid, int b0,
                                           float* __restrict__ outp, int t) {
  float4 ha = h2buf[tid];
  float4 hb = h2buf[tid + 64];
  float p0 = wo0 * ha.x + wo1 * hb.x;
  float p1 = wo0 * ha.y + wo1 * hb.y;
  float p2 = wo0 * ha.z + wo1 * hb.z;
  float p3 = wo0 * ha.w + wo1 * hb.w;
#pragma unroll
  for (int off = 1; off < 64; off <<= 1) {
    p0 += __shfl_xor(p0, off, 64);
    p1 += __shfl_xor(p1, off, 64);
    p2 += __shfl_xor(p2, off, 64);
    p3 += __shfl_xor(p3, off, 64);
  }
  if (tid < BCH) {
    float v = (tid == 0) ? p0 : (tid == 1) ? p1 : (tid == 2) ? p2 : p3;
    outp[(size_t)(b0 + tid) * T_LEN + t] = v + bo;
  }
}

__global__ void __launch_bounds__(512) lstm_fused(
    const float* __restrict__ xin, const float* __restrict__ Wih1,
    const float* __restrict__ bih1, const float* __restrict__ bhh1,
    const float* __restrict__ Whh1, const float* __restrict__ Wih2,
    const float* __restrict__ Whh2, int sk, int sj,
    const float* __restrict__ bih2, const float* __restrict__ bhh2,
    const float* __restrict__ Wout, const float* __restrict__ bout,
    float* __restrict__ outp) {
  __shared__ float4 h1buf[HID];
  __shared__ float4 h2buf[HID];
  __shared__ float4 g1[G4];
  __shared__ float4 g2[G4];
  __shared__ float xb[2][BCH];

  const int tid = threadIdx.x;
  const int b0 = blockIdx.x * BCH;
  const int gt = tid >> 7;

  float bias1 = bih1[tid] + bhh1[tid];
  float bias2 = bih2[tid] + bhh2[tid];
  float wi1 = Wih1[tid];
  float c1_0 = 0.f, c1_1 = 0.f, c1_2 = 0.f, c1_3 = 0.f;
  float c2_0 = 0.f, c2_1 = 0.f, c2_2 = 0.f, c2_3 = 0.f;
  float wo0 = 0.f, wo1 = 0.f, bo = 0.f;
  if (tid < 64) { wo0 = Wout[tid]; wo1 = Wout[tid + 64]; bo = bout[0]; }
  if (tid < HID) {
    h1buf[tid] = make_float4(0.f, 0.f, 0.f, 0.f);
    h2buf[tid] = make_float4(0.f, 0.f, 0.f, 0.f);
  }
  if (tid < BCH) xb[0][tid] = xin[(b0 + tid) * T_LEN];
  __syncthreads();

  const float* wp1  = Whh1 + tid * sj;
  const float* wp2  = Whh2 + tid * sj;
  const float* wpi2 = Wih2 + tid * sj;

  for (int t = 0; t < T_LEN; ++t) {
    float xpref = 0.f;
    if ((tid & ~3) == 128 && (t + 1) < T_LEN)
      xpref = xin[(b0 + (tid & 3)) * T_LEN + t + 1];

    if (tid < 64 && t > 0) store_out4(h2buf, wo0, wo1, bo, tid, b0, outp, t - 1);

    float xv0 = xb[t & 1][0], xv1 = xb[t & 1][1];
    float xv2 = xb[t & 1][2], xv3 = xb[t & 1][3];
    float a10 = fmaf(wi1, xv0, bias1);
    float a11 = fmaf(wi1, xv1, bias1);
    float a12 = fmaf(wi1, xv2, bias1);
    float a13 = fmaf(wi1, xv3, bias1);
    float a20 = bias2, a21 = bias2, a22 = bias2, a23 = bias2;
#pragma unroll 8
    for (int k = 0; k < HID; ++k) {
      float w1 = wp1[k * sk];
      float w2 = wp2[k * sk];
      float4 hv1 = h1buf[k];
      float4 hv2 = h2buf[k];
      a10 = fmaf(w1, hv1.x, a10);
      a11 = fmaf(w1, hv1.y, a11);
      a12 = fmaf(w1, hv1.z, a12);
      a13 = fmaf(w1, hv1.w, a13);
      a20 = fmaf(w2, hv2.x, a20);
      a21 = fmaf(w2, hv2.y, a21);
      a22 = fmaf(w2, hv2.z, a22);
      a23 = fmaf(w2, hv2.w, a23);
    }
    float4 A1v;
    A1v.x = gact(a10, gt); A1v.y = gact(a11, gt);
    A1v.z = gact(a12, gt); A1v.w = gact(a13, gt);
    g1[tid] = A1v;
    __syncthreads();

    if (tid < HID) {
      float4 iv = g1[tid], fv = g1[tid + HID];
      float4 gv = g1[tid + 2 * HID], ov = g1[tid + 3 * HID];
      c1_0 = fmaf(fv.x, c1_0, iv.x * gv.x);
      c1_1 = fmaf(fv.y, c1_1, iv.y * gv.y);
      c1_2 = fmaf(fv.z, c1_2, iv.z * gv.z);
      c1_3 = fmaf(fv.w, c1_3, iv.w * gv.w);
      float4 h;
      h.x = ov.x * ftanh(c1_0);
      h.y = ov.y * ftanh(c1_1);
      h.z = ov.z * ftanh(c1_2);
      h.w = ov.w * ftanh(c1_3);
      h1buf[tid] = h;
    }
    __syncthreads();

#pragma unroll 8
    for (int k = 0; k < HID; ++k) {
      float wv = wpi2[k * sk];
      float4 hv = h1buf[k];
      a20 = fmaf(wv, hv.x, a20);
      a21 = fmaf(wv, hv.y, a21);
      a22 = fmaf(wv, hv.z, a22);
      a23 = fmaf(wv, hv.w, a23);
    }
    float4 A2v;
    A2v.x = gact(a20, gt); A2v.y = gact(a21, gt);
    A2v.z = gact(a22, gt); A2v.w = gact(a23, gt);
    g2[tid] = A2v;
    __syncthreads();

    if (tid < HID) {
      float4 iv = g2[tid], fv = g2[tid + HID];
      float4 gv = g2[tid + 2 * HID], ov = g2[tid + 3 * HID];
      c2_0 = fmaf(fv.x, c2_0, iv.x * gv.x);
      c2_1 = fmaf(fv.y, c2_1, iv.y * gv.y);
      c2_2 = fmaf(fv.z, c2_2, iv.z * gv.z);
      c2_3 = fmaf(fv.w, c2_3, iv.w * gv.w);
      float4 h;
      h.x = ov.x * ftanh(c2_0);
      h.y = ov.y * ftanh(c2_1);
      h.z = ov.z * ftanh(c2_2);
      h.w = ov.w * ftanh(c2_3);
      h2buf[tid] = h;
    } else if ((tid & ~3) == 128 && (t + 1) < T_LEN) {
      xb[(t + 1) & 1][tid & 3] = xpref;
    }
    __syncthreads();
  }
  if (tid < 64) store_out4(h2buf, wo0, wo1, bo, tid, b0, outp, T_LEN - 1);
}

extern "C" void kernel_launch(void* const* d_in, const int* in_sizes, int n_in,
                              void* d_out, int out_size, void* d_ws, size_t ws_size,
                              hipStream_t stream) {
  const float* xin  = (const float*)d_in[0];
  const float* Wih1 = (const float*)d_in[1];
  const float* Whh1 = (const float*)d_in[2];
  const float* bih1 = (const float*)d_in[3];
  const float* bhh1 = (const float*)d_in[4];
  const float* Wih2 = (const float*)d_in[5];
  const float* Whh2 = (const float*)d_in[6];
  const float* bih2 = (const float*)d_in[7];
  const float* bhh2 = (const float*)d_in[8];
  const float* Wout = (const float*)d_in[9];
  const float* bout = (const float*)d_in[10];
  float* outp = (float*)d_out;

  const size_t needFr = (size_t)3 * 8 * 16 * 64 * sizeof(uint4);  // 384 KB
  if (ws_size >= needFr) {
    uint4* wfrag = (uint4*)d_ws;
    pack_frag2<<<96, 256, 0, stream>>>(Whh1, Whh2, Wih2, wfrag);
    lstm_pipe<<<NG, 512, 0, stream>>>(
        xin, Wih1, bih1, bhh1, wfrag, bih2, bhh2, Wout, bout, outp);
    return;
  }

  // fallback: round-1 fp32 kernel
  size_t need = (size_t)3 * G4 * HID * sizeof(float);
  if (ws_size >= need) {
    float* wt = (float*)d_ws;
    transpose_w<<<dim3(128, 3), 512, 0, stream>>>(Whh1, Wih2, Whh2, wt);
    lstm_fused<<<NG, 512, 0, stream>>>(
        xin, Wih1, bih1, bhh1,
        wt, wt + (size_t)G4 * HID, wt + (size_t)2 * G4 * HID, G4, 1,
        bih2, bhh2, Wout, bout, outp);
  } else {
    lstm_fused<<<NG, 512, 0, stream>>>(
        xin, Wih1, bih1, bhh1,
        Whh1, Wih2, Whh2, 1, HID,
        bih2, bhh2, Wout, bout, outp);
  }
}